// Round 5
// baseline (494.852 us; speedup 1.0000x reference)
//
#include <hip/hip_runtime.h>
#include <cstdint>
#include <math.h>

#define BB 256
#define CC 64
#define TT 4000
#define NHID 64
#define NOUT 64
#define NMLP (NOUT*(CC+1))  // 4160
#define TCH 128             // t per k_apply block

// ---------------- K1: fused per-channel log-variance + MLP hypernetwork ----------------
// grid 256 (one block per sample b), block 1024. 16 threads per channel row.
// Produces wsB[b][o] and transposed wsW[b][c][o].
__global__ __launch_bounds__(1024) void k_feat(const float* __restrict__ x,
                                               const float* __restrict__ W1,
                                               const float* __restrict__ b1,
                                               const float* __restrict__ W2,
                                               const float* __restrict__ b2,
                                               float* __restrict__ wsW,
                                               float* __restrict__ wsB) {
    int b   = blockIdx.x;
    int tid = threadIdx.x;
    int c   = tid >> 4;      // 0..63
    int sub = tid & 15;      // 0..15

    const float4* row = (const float4*)(x + (size_t)b * (CC * TT) + (size_t)c * TT);
    float s = 0.f, ss = 0.f;
    #pragma unroll 4
    for (int i = sub; i < TT / 4; i += 16) {   // 1000 float4 per row / 16 threads
        float4 v = row[i];
        s  += v.x + v.y + v.z + v.w;
        ss += v.x * v.x + v.y * v.y + v.z * v.z + v.w * v.w;
    }
    #pragma unroll
    for (int off = 8; off > 0; off >>= 1) {
        s  += __shfl_xor(s, off);
        ss += __shfl_xor(ss, off);
    }

    __shared__ float fs[CC];
    __shared__ float hs[NHID];
    if (sub == 0) {
        float var = (ss - s * s / (float)TT) / (float)(TT - 1);
        float f = logf(var);
        if (isinf(f) && f < 0.f) f = 0.f;   // jnp.where(isneginf, 0, .)
        fs[c] = f;
    }
    __syncthreads();

    if (tid < NHID) {
        float v = b1[tid];
        #pragma unroll 8
        for (int k = 0; k < CC; ++k) v = fmaf(fs[k], W1[k * NHID + tid], v);
        hs[tid] = v > 0.f ? v : 0.f;
    }
    __syncthreads();

    for (int j = tid; j < NMLP; j += 1024) {
        float v = b2[j];
        #pragma unroll 8
        for (int k = 0; k < NHID; ++k) v = fmaf(hs[k], W2[k * NMLP + j], v);
        if (j < NOUT) {
            wsB[b * NOUT + j] = v;
        } else {
            int kk = j - NOUT;
            int o = kk >> 6, c2 = kk & 63;           // mlp_out[64 + o*64 + c] = W[o][c]
            wsW[(size_t)b * 4096 + c2 * 64 + o] = v; // store transposed [c][o]
        }
    }
}

// ---------------- K2: out[b,o,t] = sum_c W[o,c]*x[b,c,t] + bias[o] ----------------
// grid (32, 256), block 256 (4 waves). x tile [64 c][128 t] in LDS (32 KB, 5
// blocks/CU). Wave w computes o in [16w,16w+16). ob0 forced into an SGPR via
// readfirstlane so the W/bias reads are PROVABLY wave-uniform -> s_load
// (R4 bug: threadIdx-derived ob0 made them divergent global_load_dword).
__global__ __launch_bounds__(256) void k_apply(const float* __restrict__ x,
                                               const float* __restrict__ wsW,
                                               const float* __restrict__ wsB,
                                               float* __restrict__ out) {
    int b    = (BB - 1) - blockIdx.y;
    int tb   = blockIdx.x * TCH;
    int tid  = threadIdx.x;
    int wave = tid >> 6, lane = tid & 63;
    int nv   = (TT - tb) < TCH ? (TT - tb) : TCH;   // valid t in chunk (32 or 128)

    __shared__ float xs[CC][TCH];

    // ---- stage x[b][:, tb..tb+nv) : 2048 float4, 8 per thread ----
    const float* xb = x + (size_t)b * (CC * TT) + tb;
    #pragma unroll
    for (int r = 0; r < 8; ++r) {
        int idx = r * 256 + tid;
        int c   = idx >> 5;                 // 32 float4 per row
        int pos = (idx & 31) * 4;
        int posc = pos < nv ? pos : (nv - 4);
        float4 v = *(const float4*)(xb + (size_t)c * TT + posc);
        *(float4*)&xs[c][pos] = v;
    }
    __syncthreads();

    // force wave-uniform o-base into SGPR so W/bias loads scalarize
    int ob0 = __builtin_amdgcn_readfirstlane(wave * 16);

    const float* wb = wsW + (size_t)b * 4096 + ob0;   // uniform -> s_load, [c][o]
    const float* bb = wsB + (size_t)b * 64 + ob0;     // uniform -> s_load

    float2 acc[16];
    #pragma unroll
    for (int o = 0; o < 16; ++o) {
        float bv = bb[o];
        acc[o].x = bv; acc[o].y = bv;
    }

    #pragma unroll
    for (int c = 0; c < CC; ++c) {
        float2 xv = *(const float2*)&xs[c][lane * 2];
        const float* wrow = wb + c * 64;    // uniform row -> s_load_dwordx16
        #pragma unroll
        for (int o = 0; o < 16; ++o) {
            float w = wrow[o];
            acc[o].x = fmaf(w, xv.x, acc[o].x);
            acc[o].y = fmaf(w, xv.y, acc[o].y);
        }
    }

    int t0 = lane * 2;
    if (t0 < nv) {
        float* op = out + (size_t)b * (NOUT * TT) + tb + t0;
        #pragma unroll
        for (int o = 0; o < 16; ++o)
            *(float2*)(op + (size_t)(ob0 + o) * TT) = acc[o];
    }
}

extern "C" void kernel_launch(void* const* d_in, const int* in_sizes, int n_in,
                              void* d_out, int out_size, void* d_ws, size_t ws_size,
                              hipStream_t stream) {
    const float* x  = (const float*)d_in[0];
    const float* W1 = (const float*)d_in[1];
    const float* b1 = (const float*)d_in[2];
    const float* W2 = (const float*)d_in[3];
    const float* b2 = (const float*)d_in[4];
    float* out = (float*)d_out;
    float* ws  = (float*)d_ws;

    float* wsB = ws;              // 256*64   = 16384 floats
    float* wsW = ws + 16384;      // 256*4096 = 1048576 floats

    k_feat<<<256, 1024, 0, stream>>>(x, W1, b1, W2, b2, wsW, wsB);
    k_apply<<<dim3(32, 256), 256, 0, stream>>>(x, wsW, wsB, out);
}

// Round 6
// 492.421 us; speedup vs baseline: 1.0049x; 1.0049x over previous
//
#include <hip/hip_runtime.h>
#include <cstdint>
#include <math.h>

#define BB 256
#define CC 64
#define TT 4000
#define NHID 64
#define NOUT 64
#define NMLP (NOUT*(CC+1))  // 4160

// ---------------- K1: fused per-channel log-variance + MLP hypernetwork ----------------
// grid 256 (one block per sample b), block 1024. 16 threads per channel row.
// Produces wsB[b][o] and wsW[b][o][c] (NATURAL layout, no transpose).
__global__ __launch_bounds__(1024) void k_feat(const float* __restrict__ x,
                                               const float* __restrict__ W1,
                                               const float* __restrict__ b1,
                                               const float* __restrict__ W2,
                                               const float* __restrict__ b2,
                                               float* __restrict__ wsW,
                                               float* __restrict__ wsB) {
    int b   = blockIdx.x;
    int tid = threadIdx.x;
    int c   = tid >> 4;      // 0..63
    int sub = tid & 15;      // 0..15

    const float4* row = (const float4*)(x + (size_t)b * (CC * TT) + (size_t)c * TT);
    float s = 0.f, ss = 0.f;
    #pragma unroll 4
    for (int i = sub; i < TT / 4; i += 16) {   // 1000 float4 per row / 16 threads
        float4 v = row[i];
        s  += v.x + v.y + v.z + v.w;
        ss += v.x * v.x + v.y * v.y + v.z * v.z + v.w * v.w;
    }
    #pragma unroll
    for (int off = 8; off > 0; off >>= 1) {
        s  += __shfl_xor(s, off);
        ss += __shfl_xor(ss, off);
    }

    __shared__ float fs[CC];
    __shared__ float hs[NHID];
    if (sub == 0) {
        float var = (ss - s * s / (float)TT) / (float)(TT - 1);
        float f = logf(var);
        if (isinf(f) && f < 0.f) f = 0.f;   // jnp.where(isneginf, 0, .)
        fs[c] = f;
    }
    __syncthreads();

    if (tid < NHID) {
        float v = b1[tid];
        #pragma unroll 8
        for (int k = 0; k < CC; ++k) v = fmaf(fs[k], W1[k * NHID + tid], v);
        hs[tid] = v > 0.f ? v : 0.f;
    }
    __syncthreads();

    for (int j = tid; j < NMLP; j += 1024) {
        float v = b2[j];
        #pragma unroll 8
        for (int k = 0; k < NHID; ++k) v = fmaf(hs[k], W2[k * NMLP + j], v);
        if (j < NOUT) {
            wsB[b * NOUT + j] = v;
        } else {
            wsW[(size_t)b * 4096 + (j - NOUT)] = v;  // natural [o][c]
        }
    }
}

// ---------------- K2: out[b,o,t] = sum_c W[o,c]*x[b,c,t] + bias[o] ----------------
// grid (16, 256), block 256. NO LDS. x held in registers xr[64] (read once,
// vmcnt); W rows are block-uniform -> s_load (lgkmcnt, nothing else on that
// counter); each output stored immediately. Two interleaved o-chains hide
// fmac dep latency even at low wave count.
__global__ __launch_bounds__(256) void k_apply(const float* __restrict__ x,
                                               const float* __restrict__ wsW,
                                               const float* __restrict__ wsB,
                                               float* __restrict__ out) {
    int b   = (BB - 1) - blockIdx.y;
    int t   = blockIdx.x * 256 + threadIdx.x;   // 0..4095, 4000 valid
    bool valid = t < TT;
    int tc  = valid ? t : (TT - 1);

    const float* xb = x + (size_t)b * (CC * TT) + tc;
    float xr[CC];
    #pragma unroll
    for (int c = 0; c < CC; ++c) xr[c] = xb[(size_t)c * TT];

    const float* wb = wsW + (size_t)b * 4096;   // uniform -> s_load
    const float* bb = wsB + (size_t)b * 64;     // uniform -> s_load

    if (!valid) return;
    float* ob = out + (size_t)b * (NOUT * TT) + t;

    #pragma unroll 1
    for (int o = 0; o < NOUT; o += 2) {
        float a0 = bb[o];
        float a1 = bb[o + 1];
        const float* w0 = wb + (size_t)o * 64;
        const float* w1 = w0 + 64;
        #pragma unroll
        for (int c = 0; c < CC; ++c) {
            a0 = fmaf(w0[c], xr[c], a0);
            a1 = fmaf(w1[c], xr[c], a1);
        }
        ob[(size_t)o * TT]       = a0;
        ob[(size_t)(o + 1) * TT] = a1;
    }
}

extern "C" void kernel_launch(void* const* d_in, const int* in_sizes, int n_in,
                              void* d_out, int out_size, void* d_ws, size_t ws_size,
                              hipStream_t stream) {
    const float* x  = (const float*)d_in[0];
    const float* W1 = (const float*)d_in[1];
    const float* b1 = (const float*)d_in[2];
    const float* W2 = (const float*)d_in[3];
    const float* b2 = (const float*)d_in[4];
    float* out = (float*)d_out;
    float* ws  = (float*)d_ws;

    float* wsB = ws;              // 256*64   = 16384 floats
    float* wsW = ws + 16384;      // 256*4096 = 1048576 floats

    k_feat<<<256, 1024, 0, stream>>>(x, W1, b1, W2, b2, wsW, wsB);
    k_apply<<<dim3(16, 256), 256, 0, stream>>>(x, wsW, wsB, out);
}

// Round 7
// 198.097 us; speedup vs baseline: 2.4980x; 2.4858x over previous
//
#include <hip/hip_runtime.h>
#include <hip/hip_bf16.h>
#include <cstdint>
#include <math.h>

#define BB 256
#define CC 64
#define TT 4000
#define NHID 64
#define NOUT 64
#define NMLP (NOUT*(CC+1))  // 4160
#define TCH 256             // t per k_apply block

// ---------------- K1: fused per-channel log-variance + MLP hypernetwork ----------------
// grid 256 (one block per sample b), block 1024. 16 threads per channel row.
// Produces wsB[b][o] (fp32) and wtg[b][c][o] (bf16, TRANSPOSED for k_apply LDS reads).
__global__ __launch_bounds__(1024) void k_feat(const float* __restrict__ x,
                                               const float* __restrict__ W1,
                                               const float* __restrict__ b1,
                                               const float* __restrict__ W2,
                                               const float* __restrict__ b2,
                                               __hip_bfloat16* __restrict__ wtg,
                                               float* __restrict__ wsB) {
    int b   = blockIdx.x;
    int tid = threadIdx.x;
    int c   = tid >> 4;      // 0..63
    int sub = tid & 15;      // 0..15

    const float4* row = (const float4*)(x + (size_t)b * (CC * TT) + (size_t)c * TT);
    float s = 0.f, ss = 0.f;
    #pragma unroll 4
    for (int i = sub; i < TT / 4; i += 16) {   // 1000 float4 per row / 16 threads
        float4 v = row[i];
        s  += v.x + v.y + v.z + v.w;
        ss += v.x * v.x + v.y * v.y + v.z * v.z + v.w * v.w;
    }
    #pragma unroll
    for (int off = 8; off > 0; off >>= 1) {
        s  += __shfl_xor(s, off);
        ss += __shfl_xor(ss, off);
    }

    __shared__ float fs[CC];
    __shared__ float hs[NHID];
    if (sub == 0) {
        float var = (ss - s * s / (float)TT) / (float)(TT - 1);
        float f = logf(var);
        if (isinf(f) && f < 0.f) f = 0.f;   // jnp.where(isneginf, 0, .)
        fs[c] = f;
    }
    __syncthreads();

    if (tid < NHID) {
        float v = b1[tid];
        #pragma unroll 8
        for (int k = 0; k < CC; ++k) v = fmaf(fs[k], W1[k * NHID + tid], v);
        hs[tid] = v > 0.f ? v : 0.f;
    }
    __syncthreads();

    for (int j = tid; j < NMLP; j += 1024) {
        float v = b2[j];
        #pragma unroll 8
        for (int k = 0; k < NHID; ++k) v = fmaf(hs[k], W2[k * NMLP + j], v);
        if (j < NOUT) {
            wsB[b * NOUT + j] = v;
        } else {
            int kk = j - NOUT;
            int o = kk >> 6, c2 = kk & 63;               // mlp_out[64+o*64+c] = W[o][c]
            wtg[(size_t)b * 4096 + c2 * 64 + o] = __float2bfloat16(v);  // [c][o] bf16
        }
    }
}

// ---------------- K2: out[b,o,t] = sum_c W[o,c]*x[b,c,t] + bias[o] ----------------
// grid (16, 256), block 256. Register-blocked 8x8 patch per thread:
// og=tid&7 (8 o's), tg=tid>>3 (8 t's). x fp32 [64][256] (64KB) + W bf16 [c][o]
// (8KB) in LDS -> 2 blocks/CU. Per c: 1 uint4 W read + 2 ds_read_b128 x + 64 FMA.
// Pure-LDS operands -> fine-grained lgkmcnt, no SMEM mixing, no divergent global.
__global__ __launch_bounds__(256, 2) void k_apply(const float* __restrict__ x,
                                                  const __hip_bfloat16* __restrict__ wtg,
                                                  const float* __restrict__ wsB,
                                                  float* __restrict__ out) {
    int b   = (BB - 1) - blockIdx.y;    // reversed: reuse x tail from k_feat in L3
    int tb  = blockIdx.x * TCH;
    int tid = threadIdx.x;

    __shared__ float          xs[CC][TCH];   // 64 KB
    __shared__ unsigned short wt[CC][64];    // 8 KB, [c][o] bf16
    __shared__ float          bl[64];

    // ---- stage x[b][:, tb..tb+256): wave reads 1KB contiguous per instr ----
    const float* xb = x + (size_t)b * (CC * TT) + tb;
    int maxf4 = ((TT - tb) >> 2) - 1;        // 63 normally, 39 on tail chunk
    #pragma unroll
    for (int k = 0; k < 16; ++k) {
        int idx = k * 256 + tid;
        int c   = idx >> 6;
        int f4  = idx & 63;
        int f4c = f4 < maxf4 ? f4 : maxf4;
        float4 v = *(const float4*)(xb + (size_t)c * TT + f4c * 4);
        *(float4*)&xs[c][f4 * 4] = v;
    }
    // ---- stage W (8 KB bf16) + bias ----
    const uint4* wg = (const uint4*)(wtg + (size_t)b * 4096);
    #pragma unroll
    for (int k = 0; k < 2; ++k)
        ((uint4*)wt)[k * 256 + tid] = wg[k * 256 + tid];
    if (tid < 16)
        ((float4*)bl)[tid] = ((const float4*)(wsB + b * 64))[tid];
    __syncthreads();

    int og = tid & 7;        // o-block: o = og*8 + oo
    int tg = tid >> 3;       // t-block: t = tb + tg*8 + j

    float acc[8][8];
    {
        float4 b0 = *(const float4*)&bl[og * 8];
        float4 b1v = *(const float4*)&bl[og * 8 + 4];
        float bv[8] = {b0.x, b0.y, b0.z, b0.w, b1v.x, b1v.y, b1v.z, b1v.w};
        #pragma unroll
        for (int oo = 0; oo < 8; ++oo)
            #pragma unroll
            for (int j = 0; j < 8; ++j) acc[oo][j] = bv[oo];
    }

    #pragma unroll 2
    for (int c = 0; c < CC; ++c) {
        uint4  wraw = *(const uint4*)&wt[c][og * 8];
        float4 xa   = *(const float4*)&xs[c][tg * 8];
        float4 xc   = *(const float4*)&xs[c][tg * 8 + 4];
        float w[8];
        w[0] = __uint_as_float(wraw.x << 16);
        w[1] = __uint_as_float(wraw.x & 0xFFFF0000u);
        w[2] = __uint_as_float(wraw.y << 16);
        w[3] = __uint_as_float(wraw.y & 0xFFFF0000u);
        w[4] = __uint_as_float(wraw.z << 16);
        w[5] = __uint_as_float(wraw.z & 0xFFFF0000u);
        w[6] = __uint_as_float(wraw.w << 16);
        w[7] = __uint_as_float(wraw.w & 0xFFFF0000u);
        float xv[8] = {xa.x, xa.y, xa.z, xa.w, xc.x, xc.y, xc.z, xc.w};
        #pragma unroll
        for (int oo = 0; oo < 8; ++oo)
            #pragma unroll
            for (int j = 0; j < 8; ++j)
                acc[oo][j] = fmaf(w[oo], xv[j], acc[oo][j]);
    }

    int t0 = tb + tg * 8;
    if (t0 < TT) {                            // tail chunk: tg>=20 masked
        float* op = out + (size_t)b * (NOUT * TT) + (size_t)(og * 8) * TT + t0;
        #pragma unroll
        for (int oo = 0; oo < 8; ++oo) {
            *(float4*)(op + (size_t)oo * TT)     = {acc[oo][0], acc[oo][1], acc[oo][2], acc[oo][3]};
            *(float4*)(op + (size_t)oo * TT + 4) = {acc[oo][4], acc[oo][5], acc[oo][6], acc[oo][7]};
        }
    }
}

extern "C" void kernel_launch(void* const* d_in, const int* in_sizes, int n_in,
                              void* d_out, int out_size, void* d_ws, size_t ws_size,
                              hipStream_t stream) {
    const float* x  = (const float*)d_in[0];
    const float* W1 = (const float*)d_in[1];
    const float* b1 = (const float*)d_in[2];
    const float* W2 = (const float*)d_in[3];
    const float* b2 = (const float*)d_in[4];
    float* out = (float*)d_out;
    float* ws  = (float*)d_ws;

    float*           wsB = ws;                              // 256*64 fp32
    __hip_bfloat16*  wtg = (__hip_bfloat16*)(ws + 16384);   // 256*4096 bf16 (2 MB)

    k_feat<<<256, 1024, 0, stream>>>(x, W1, b1, W2, b2, wtg, wsB);
    k_apply<<<dim3(16, 256), 256, 0, stream>>>(x, wtg, wsB, out);
}